// Round 3
// baseline (385.163 us; speedup 1.0000x reference)
//
#include <hip/hip_runtime.h>
#include <stdint.h>

#define NTOK 8192
#define DIM 1024
#define EDIM 2048

typedef __attribute__((ext_vector_type(8))) short bf16x8;
typedef __attribute__((ext_vector_type(4))) float f32x4;

__device__ __forceinline__ unsigned short f2bf(float f) {
  union { float f; unsigned u; } v; v.f = f;
  unsigned r = (v.u + 0x7FFF + ((v.u >> 16) & 1)) >> 16;
  return (unsigned short)r;
}

__device__ __forceinline__ void gload16(const void* g, void* l) {
  __builtin_amdgcn_global_load_lds(
      (const __attribute__((address_space(1))) unsigned int*)g,
      (__attribute__((address_space(3))) unsigned int*)l, 16, 0, 0);
}

#define BARRIER() do { __builtin_amdgcn_s_barrier(); asm volatile("" ::: "memory"); } while (0)
#define VMW(n) asm volatile("s_waitcnt vmcnt(" #n ")" ::: "memory")

// ---- fused x->bf16 cast + router logits (no atomics; writes choice[n]) ------
__global__ void cvtrouter_k(const float* __restrict__ x, const float* __restrict__ Wr,
                            const float* __restrict__ bias,
                            unsigned short* __restrict__ xb, int* __restrict__ choice) {
  const int wid = threadIdx.x >> 6, lane = threadIdx.x & 63;
  const float b0 = bias[0], b1 = bias[1];
  const float2* wr = (const float2*)Wr;
  #pragma unroll
  for (int r = 0; r < 2; ++r) {
    const int n = blockIdx.x * 8 + wid * 2 + r;
    const float4* xr = (const float4*)(x + (size_t)n * DIM);
    uint2* xo = (uint2*)(xb + (size_t)n * DIM);
    float s0 = 0.f, s1 = 0.f;
    #pragma unroll
    for (int i = 0; i < 4; ++i) {
      const int idx = i * 64 + lane;
      float4 v = xr[idx];
      float2 wa = wr[idx * 4], wb = wr[idx * 4 + 1], wc = wr[idx * 4 + 2], wd = wr[idx * 4 + 3];
      s0 += v.x * wa.x + v.y * wb.x + v.z * wc.x + v.w * wd.x;
      s1 += v.x * wa.y + v.y * wb.y + v.z * wc.y + v.w * wd.y;
      union { unsigned short s[4]; uint2 u; } o;
      o.s[0] = f2bf(v.x); o.s[1] = f2bf(v.y); o.s[2] = f2bf(v.z); o.s[3] = f2bf(v.w);
      xo[idx] = o.u;
    }
    #pragma unroll
    for (int off = 32; off; off >>= 1) {
      s0 += __shfl_xor(s0, off);
      s1 += __shfl_xor(s1, off);
    }
    if (lane == 0) choice[n] = (s1 + b1 > s0 + b0) ? 1 : 0;
  }
}

// ---- single-block prefix scan: choice[] -> ordered rowlists + counts --------
__global__ void scan_k(const int* __restrict__ choice, int* __restrict__ counts,
                       int* __restrict__ rowlist) {
  const int t = threadIdx.x;            // 1024 threads, one block
  const int base = t * 8;
  int c[8]; int ones = 0;
  #pragma unroll
  for (int j = 0; j < 8; ++j) { c[j] = choice[base + j]; ones += c[j]; }
  const int lane = t & 63, wid = t >> 6;
  int v = ones;
  #pragma unroll
  for (int off = 1; off < 64; off <<= 1) {
    int o = __shfl_up(v, off);
    if (lane >= off) v += o;
  }
  __shared__ int wsum[16];
  if (lane == 63) wsum[wid] = v;
  __syncthreads();
  int pre = 0, tot = 0;
  #pragma unroll
  for (int w = 0; w < 16; ++w) {
    int s = wsum[w];
    if (w < wid) pre += s;
    tot += s;
  }
  const int excl = pre + v - ones;
  int p0 = base - excl;
  int p1 = excl;
  #pragma unroll
  for (int j = 0; j < 8; ++j) {
    if (c[j]) rowlist[NTOK + p1++] = base + j;
    else rowlist[p0++] = base + j;
  }
  if (t == 0) { counts[0] = NTOK - tot; counts[1] = tot; }
}

// ---- transpose + cast weights to bf16 [N][K]; gate/up interleaved 16-wide ---
// type 0: gate -> row (f>>4)*32 + (f&15); type 1: up -> +16; type 2: plain f
__global__ void trans_k(const float* __restrict__ Sg, const float* __restrict__ Su,
                        const float* __restrict__ Sd, const float* __restrict__ Wg,
                        const float* __restrict__ Wu, const float* __restrict__ Wd,
                        unsigned short* __restrict__ wt) {
  const int id = blockIdx.y;
  const size_t MSZ = (size_t)DIM * EDIM;
  const float* src; int R, C, type; size_t dof;
  switch (id) {
    case 0: src = Sg;       R = DIM;  C = EDIM; type = 0; dof = 0;        break;
    case 1: src = Su;       R = DIM;  C = EDIM; type = 1; dof = 0;        break;
    case 2: src = Wg;       R = DIM;  C = EDIM; type = 0; dof = 2 * MSZ;  break;
    case 3: src = Wu;       R = DIM;  C = EDIM; type = 1; dof = 2 * MSZ;  break;
    case 4: src = Wg + MSZ; R = DIM;  C = EDIM; type = 0; dof = 4 * MSZ;  break;
    case 5: src = Wu + MSZ; R = DIM;  C = EDIM; type = 1; dof = 4 * MSZ;  break;
    case 6: src = Sd;       R = EDIM; C = DIM;  type = 2; dof = 6 * MSZ;  break;
    case 7: src = Wd;       R = EDIM; C = DIM;  type = 2; dof = 7 * MSZ;  break;
    default: src = Wd + MSZ; R = EDIM; C = DIM; type = 2; dof = 8 * MSZ;  break;
  }
  unsigned short* dst = wt + dof;
  __shared__ float tile[32][33];
  int tC = C >> 5;
  int tr = blockIdx.x / tC, tc = blockIdx.x % tC;
  int xt = threadIdx.x, yt = threadIdx.y;
  #pragma unroll
  for (int j = 0; j < 4; ++j)
    tile[yt + j * 8][xt] = src[(size_t)(tr * 32 + yt + j * 8) * C + tc * 32 + xt];
  __syncthreads();
  #pragma unroll
  for (int j = 0; j < 4; ++j) {
    int f = tc * 32 + yt + j * 8;
    int row = (type == 2) ? f : (((f >> 4) << 5) + (f & 15) + (type ? 16 : 0));
    dst[(size_t)row * R + tr * 32 + xt] = f2bf(tile[xt][yt + j * 8]);
  }
}

// ---- pipelined MFMA GEMM template -------------------------------------------
// BM=256, BK=64, 512 threads (8 waves). 4 phases/K-tile, K-half sub-buffers,
// counted vmcnt (never 0 except final tile), setprio around MFMA clusters.
// EPI 0: h=silu(g)*u epilogue (interleaved B), 1: out=, 2: out+= scatter
template<int BN, int KDIM, bool GATHER, int EPI>
__global__ __launch_bounds__(512, 2)
void gemm_k(const unsigned short* __restrict__ A, const unsigned short* __restrict__ B0,
            const int* __restrict__ counts, const int* __restrict__ rowlist,
            unsigned short* __restrict__ hout, float* __restrict__ out) {
  constexpr int NT = KDIM / 64;
  constexpr int MROWS = (BN == 256) ? 128 : 64;   // rows per wave
  constexpr int MF = MROWS / 32;                  // A-frags per phase (4 or 2)
  constexpr int LB = BN / 128;                    // B gloads per half-tile
  constexpr int BSUB = BN * 64;                   // B sub-buffer bytes
  constexpr int ROWB = KDIM * 2;                  // bytes per A/B row

  int m0, cnt = NTOK, mstart = 0;
  const int* rl = nullptr;
  const unsigned short* B = B0;
  if (EPI == 0 && GATHER) {                       // routed up
    int e = blockIdx.x >> 5, mt = blockIdx.x & 31;
    cnt = counts[e];
    if (mt * 256 >= cnt) return;
    rl = rowlist + e * NTOK;
    mstart = e ? counts[0] : 0;
    m0 = mt * 256;
    B = B0 + (size_t)e * (2u * (size_t)DIM * EDIM);
  } else if (EPI == 2) {                          // routed down (compacted h)
    int e = blockIdx.x >> 5, mt = blockIdx.x & 31;
    cnt = counts[e];
    if (mt * 256 >= cnt) return;
    rl = rowlist + e * NTOK;
    mstart = e ? counts[0] : 0;
    m0 = mstart + mt * 256;
    B = B0 + (size_t)e * ((size_t)DIM * EDIM);
  } else {
    m0 = blockIdx.x * 256;
  }
  const int n0 = blockIdx.y * BN;

  __shared__ __align__(16) unsigned char ldsA[65536];        // 2dbuf x 2kh x 16KB
  __shared__ __align__(16) unsigned char ldsB[4 * BSUB];

  const int t_ = threadIdx.x;
  const int lane = t_ & 63;
  const int wid = t_ >> 6;
  const int wm = (BN == 256) ? (wid >> 2) : (wid >> 1);
  const int wn = (BN == 256) ? (wid & 3) : (wid & 1);
  const int l15 = lane & 15, l4 = lane >> 4;

  // staging source/dest precompute (linear LDS dest; source pre-permuted so
  // swizzled reads see data(row, kchunk) at slot ((row&1)*4+kc)^(line&7))
  uint32_t srcA[2]; int dstA[2];
  #pragma unroll
  for (int i = 0; i < 2; ++i) {
    int line = i * 64 + (t_ >> 3);
    int sl = (t_ & 7) ^ (line & 7);
    int ra = 2 * line + (sl >> 2), kc = sl & 3;
    int grow;
    if (EPI == 0 && GATHER) {
      int idx = m0 + ra; if (idx >= cnt) idx = cnt - 1;
      grow = rl[idx];
    } else {
      grow = m0 + ra; if (grow > NTOK - 1) grow = NTOK - 1;
    }
    srcA[i] = (uint32_t)grow * ROWB + kc * 16;
    dstA[i] = i * 8192 + t_ * 16;
  }
  uint32_t srcB[LB]; int dstB[LB];
  #pragma unroll
  for (int i = 0; i < LB; ++i) {
    int line = i * 64 + (t_ >> 3);
    int sl = (t_ & 7) ^ (line & 7);
    int rb = 2 * line + (sl >> 2), kc = sl & 3;
    srcB[i] = (uint32_t)(n0 + rb) * ROWB + kc * 16;
    dstB[i] = i * 8192 + t_ * 16;
  }

  const char* Ab = (const char*)A;
  const char* Bb = (const char*)B;
  auto issueA = [&](int kt, int kh) {
    if (kt >= NT) return;
    char* dst = (char*)ldsA + ((kt & 1) * 2 + kh) * 16384;
    #pragma unroll
    for (int i = 0; i < 2; ++i)
      gload16(Ab + srcA[i] + kt * 128 + kh * 64, dst + dstA[i]);
  };
  auto issueB = [&](int kt, int kh) {
    if (kt >= NT) return;
    char* dst = (char*)ldsB + ((kt & 1) * 2 + kh) * BSUB;
    #pragma unroll
    for (int i = 0; i < LB; ++i)
      gload16(Bb + srcB[i] + kt * 128 + kh * 64, dst + dstB[i]);
  };
  auto ldfrag = [&](const unsigned char* sub, int row) -> bf16x8 {
    int line = row >> 1;
    int s = (((row & 1) << 2) | l4) ^ (line & 7);
    return *(const bf16x8*)(sub + line * 128 + s * 16);
  };

  f32x4 acc[2 * MF][4];
  #pragma unroll
  for (int i = 0; i < 2 * MF; ++i)
    #pragma unroll
    for (int j = 0; j < 4; ++j) acc[i][j] = f32x4{0.f, 0.f, 0.f, 0.f};

  // prologue: stage tile 0 fully; allow its kh1 (and nothing else) in flight
  issueA(0, 0); issueB(0, 0); issueA(0, 1); issueB(0, 1);
  if (BN == 256) { VMW(4); } else { VMW(3); }
  BARRIER();

  for (int kt = 0; kt < NT; ++kt) {
    const unsigned char* As0 = ldsA + ((kt & 1) * 2 + 0) * 16384;
    const unsigned char* As1 = ldsA + ((kt & 1) * 2 + 1) * 16384;
    const unsigned char* Bs0 = ldsB + ((kt & 1) * 2 + 0) * BSUB;
    const unsigned char* Bs1 = ldsB + ((kt & 1) * 2 + 1) * BSUB;
    bf16x8 aR[MF], bR[4];
    // phase 0: C-half 0, k-half 0 ; prefetch A-k0(kt+1)
    #pragma unroll
    for (int m = 0; m < MF; ++m) aR[m] = ldfrag(As0, wm * MROWS + m * 16 + l15);
    #pragma unroll
    for (int n = 0; n < 4; ++n) bR[n] = ldfrag(Bs0, wn * 64 + n * 16 + l15);
    issueA(kt + 1, 0);
    __builtin_amdgcn_s_setprio(1);
    #pragma unroll
    for (int m = 0; m < MF; ++m)
      #pragma unroll
      for (int n = 0; n < 4; ++n)
        acc[m][n] = __builtin_amdgcn_mfma_f32_16x16x32_bf16(aR[m], bR[n], acc[m][n], 0, 0, 0);
    __builtin_amdgcn_s_setprio(0);
    BARRIER();
    // phase 1: C-half 1, k-half 0 ; prefetch B-k0(kt+1); gate kh1(kt)
    #pragma unroll
    for (int m = 0; m < MF; ++m) aR[m] = ldfrag(As0, wm * MROWS + MROWS / 2 + m * 16 + l15);
    issueB(kt + 1, 0);
    __builtin_amdgcn_s_setprio(1);
    #pragma unroll
    for (int m = 0; m < MF; ++m)
      #pragma unroll
      for (int n = 0; n < 4; ++n)
        acc[MF + m][n] = __builtin_amdgcn_mfma_f32_16x16x32_bf16(aR[m], bR[n], acc[MF + m][n], 0, 0, 0);
    __builtin_amdgcn_s_setprio(0);
    if (kt + 1 < NT) { if (BN == 256) { VMW(4); } else { VMW(3); } } else { VMW(0); }
    BARRIER();
    // phase 2: C-half 0, k-half 1 ; prefetch A-k1(kt+1)
    #pragma unroll
    for (int m = 0; m < MF; ++m) aR[m] = ldfrag(As1, wm * MROWS + m * 16 + l15);
    #pragma unroll
    for (int n = 0; n < 4; ++n) bR[n] = ldfrag(Bs1, wn * 64 + n * 16 + l15);
    issueA(kt + 1, 1);
    __builtin_amdgcn_s_setprio(1);
    #pragma unroll
    for (int m = 0; m < MF; ++m)
      #pragma unroll
      for (int n = 0; n < 4; ++n)
        acc[m][n] = __builtin_amdgcn_mfma_f32_16x16x32_bf16(aR[m], bR[n], acc[m][n], 0, 0, 0);
    __builtin_amdgcn_s_setprio(0);
    BARRIER();
    // phase 3: C-half 1, k-half 1 ; prefetch B-k1(kt+1); gate kh0(kt+1)
    #pragma unroll
    for (int m = 0; m < MF; ++m) aR[m] = ldfrag(As1, wm * MROWS + MROWS / 2 + m * 16 + l15);
    issueB(kt + 1, 1);
    __builtin_amdgcn_s_setprio(1);
    #pragma unroll
    for (int m = 0; m < MF; ++m)
      #pragma unroll
      for (int n = 0; n < 4; ++n)
        acc[MF + m][n] = __builtin_amdgcn_mfma_f32_16x16x32_bf16(aR[m], bR[n], acc[MF + m][n], 0, 0, 0);
    __builtin_amdgcn_s_setprio(0);
    if (kt + 1 < NT) {
      if (BN == 256) { VMW(4); } else { VMW(3); }
      BARRIER();
    }
  }

  // epilogue
  #pragma unroll
  for (int ch = 0; ch < 2; ++ch) {
    #pragma unroll
    for (int m = 0; m < MF; ++m) {
      #pragma unroll
      for (int r = 0; r < 4; ++r) {
        const int rit = wm * MROWS + ch * (MROWS / 2) + m * 16 + l4 * 4 + r;
        if (EPI == 0) {
          const int pos = m0 + rit;
          if (GATHER && pos >= cnt) continue;
          unsigned short* hr = hout + (size_t)(mstart + pos) * EDIM;
          const int f0 = (n0 >> 1) + wn * 32;
          float g = acc[ch * MF + m][0][r], u = acc[ch * MF + m][1][r];
          hr[f0 + l15] = f2bf(g / (1.f + __expf(-g)) * u);
          g = acc[ch * MF + m][2][r]; u = acc[ch * MF + m][3][r];
          hr[f0 + 16 + l15] = f2bf(g / (1.f + __expf(-g)) * u);
        } else if (EPI == 1) {
          float* orow = out + (size_t)(m0 + rit) * DIM;
          #pragma unroll
          for (int n = 0; n < 4; ++n)
            orow[n0 + wn * 64 + n * 16 + l15] = acc[ch * MF + m][n][r];
        } else {
          const int idxe = (m0 - mstart) + rit;
          if (idxe >= cnt) continue;
          const int tok = rl[idxe];
          float* orow = out + (size_t)tok * DIM;
          #pragma unroll
          for (int n = 0; n < 4; ++n)
            orow[n0 + wn * 64 + n * 16 + l15] += acc[ch * MF + m][n][r];
        }
      }
    }
  }
}

extern "C" void kernel_launch(void* const* d_in, const int* in_sizes, int n_in,
                              void* d_out, int out_size, void* d_ws, size_t ws_size,
                              hipStream_t stream) {
  const float* x  = (const float*)d_in[0];
  const float* Wr = (const float*)d_in[1];
  const float* rb = (const float*)d_in[2];
  const float* Wg = (const float*)d_in[3];
  const float* Wu = (const float*)d_in[4];
  const float* Wd = (const float*)d_in[5];
  const float* Sg = (const float*)d_in[6];
  const float* Su = (const float*)d_in[7];
  const float* Sd = (const float*)d_in[8];
  float* out = (float*)d_out;

  const size_t MSZ = (size_t)DIM * EDIM;
  char* ws = (char*)d_ws;
  int* counts  = (int*)ws;
  int* choice  = (int*)(ws + 256);
  int* rowlist = (int*)(ws + 256 + 32768);
  unsigned short* xb = (unsigned short*)(ws + 256 + 32768 + 65536);
  unsigned short* wt = xb + (size_t)NTOK * DIM;
  unsigned short* h  = wt + 9 * MSZ;

  const unsigned short* Sgu = wt;            // [4096][1024] interleaved gate/up
  const unsigned short* Wgu = wt + 2 * MSZ;  // 2 x [4096][1024]
  const unsigned short* Sdt = wt + 6 * MSZ;  // [1024][2048]
  const unsigned short* Wdt = wt + 7 * MSZ;  // 2 x [1024][2048]

  cvtrouter_k<<<1024, 256, 0, stream>>>(x, Wr, rb, xb, choice);
  scan_k<<<1, 1024, 0, stream>>>(choice, counts, rowlist);
  trans_k<<<dim3(2048, 9), dim3(32, 8), 0, stream>>>(Sg, Su, Sd, Wg, Wu, Wd, wt);

  // shared expert
  gemm_k<256, DIM, false, 0><<<dim3(32, 16), 512, 0, stream>>>(xb, Sgu, counts, rowlist, h, nullptr);
  gemm_k<128, EDIM, false, 1><<<dim3(32, 8), 512, 0, stream>>>(h, Sdt, counts, rowlist, nullptr, out);
  // routed experts (up gathers tokens -> compacted h; down scatters += out)
  gemm_k<256, DIM, true, 0><<<dim3(64, 16), 512, 0, stream>>>(xb, Wgu, counts, rowlist, h, nullptr);
  gemm_k<128, EDIM, false, 2><<<dim3(64, 8), 512, 0, stream>>>(h, Wdt, counts, rowlist, nullptr, out);
}

// Round 4
// 280.292 us; speedup vs baseline: 1.3741x; 1.3741x over previous
//
#include <hip/hip_runtime.h>
#include <stdint.h>

#define NTOK 8192
#define DIM 1024
#define EDIM 2048

typedef __attribute__((ext_vector_type(8))) short bf16x8;
typedef __attribute__((ext_vector_type(4))) float f32x4;

__device__ __forceinline__ unsigned short f2bf(float f) {
  union { float f; unsigned u; } v; v.f = f;
  unsigned r = (v.u + 0x7FFF + ((v.u >> 16) & 1)) >> 16;
  return (unsigned short)r;
}

__device__ __forceinline__ void gload16(const void* g, void* l) {
  __builtin_amdgcn_global_load_lds(
      (const __attribute__((address_space(1))) unsigned int*)g,
      (__attribute__((address_space(3))) unsigned int*)l, 16, 0, 0);
}

// ---- mega preproc: blocks [0,1024) = x->bf16 + router logits;
// ---- blocks [1024, 1024+9*2048) = weight transpose/cast jobs --------------
__global__ void pre_k(const float* __restrict__ x, const float* __restrict__ Wr,
                      const float* __restrict__ bias,
                      const float* __restrict__ Sg, const float* __restrict__ Su,
                      const float* __restrict__ Sd, const float* __restrict__ Wg,
                      const float* __restrict__ Wu, const float* __restrict__ Wd,
                      unsigned short* __restrict__ xb, int* __restrict__ choice,
                      unsigned short* __restrict__ wt) {
  const int bx = blockIdx.x;
  const int t = threadIdx.x;
  const size_t MSZ = (size_t)DIM * EDIM;      // 2M elements
  if (bx < 1024) {
    // ---- cvt + router ----
    const int wid = t >> 6, lane = t & 63;
    const float b0 = bias[0], b1 = bias[1];
    const float2* wr = (const float2*)Wr;
    #pragma unroll
    for (int r = 0; r < 2; ++r) {
      const int n = bx * 8 + wid * 2 + r;
      const float4* xr = (const float4*)(x + (size_t)n * DIM);
      uint2* xo = (uint2*)(xb + (size_t)n * DIM);
      float s0 = 0.f, s1 = 0.f;
      #pragma unroll
      for (int i = 0; i < 4; ++i) {
        const int idx = i * 64 + lane;
        float4 v = xr[idx];
        float2 wa = wr[idx * 4], wb = wr[idx * 4 + 1], wc = wr[idx * 4 + 2], wd = wr[idx * 4 + 3];
        s0 += v.x * wa.x + v.y * wb.x + v.z * wc.x + v.w * wd.x;
        s1 += v.x * wa.y + v.y * wb.y + v.z * wc.y + v.w * wd.y;
        union { unsigned short s[4]; uint2 u; } o;
        o.s[0] = f2bf(v.x); o.s[1] = f2bf(v.y); o.s[2] = f2bf(v.z); o.s[3] = f2bf(v.w);
        xo[idx] = o.u;
      }
      #pragma unroll
      for (int off = 32; off; off >>= 1) {
        s0 += __shfl_xor(s0, off);
        s1 += __shfl_xor(s1, off);
      }
      if (lane == 0) choice[n] = (s1 + b1 > s0 + b0) ? 1 : 0;
    }
    return;
  }
  // ---- weight transpose jobs ----
  // wt layout (elems): Sgu[4M] Wgu0[4M] Wgu1[4M] Sdt[2M] Wdt0[2M] Wdt1[2M]
  const int id = bx - 1024;
  const int mat = id >> 11;          // 9 matrices x 2048 tiles
  const int tile = id & 2047;
  const float* src; unsigned short* dst; int type;
  switch (mat) {
    case 0: src = Sg;       dst = wt;            type = 0; break;
    case 1: src = Su;       dst = wt;            type = 1; break;
    case 2: src = Wg;       dst = wt + 4194304;  type = 0; break;
    case 3: src = Wu;       dst = wt + 4194304;  type = 1; break;
    case 4: src = Wg + MSZ; dst = wt + 8388608;  type = 0; break;
    case 5: src = Wu + MSZ; dst = wt + 8388608;  type = 1; break;
    case 6: src = Sd;       dst = wt + 12582912; type = 2; break;
    case 7: src = Wd;       dst = wt + 14680064; type = 2; break;
    default: src = Wd + MSZ; dst = wt + 16777216; type = 2; break;
  }
  const int R = (type == 2) ? EDIM : DIM;     // src rows
  const int C = (type == 2) ? DIM : EDIM;     // src cols
  __shared__ float ts[32][33];
  const int tC = C >> 5;
  const int tr = tile / tC, tc = tile % tC;
  const int xt = t & 31, yt = t >> 5;
  #pragma unroll
  for (int j = 0; j < 4; ++j)
    ts[yt + j * 8][xt] = src[(size_t)(tr * 32 + yt + j * 8) * C + tc * 32 + xt];
  __syncthreads();
  #pragma unroll
  for (int j = 0; j < 4; ++j) {
    const int cc = tc * 32 + yt + j * 8;     // src col
    const int rr = tr * 32 + xt;             // src row (= K index)
    const float v = ts[xt][yt + j * 8];
    if (type == 2) dst[(size_t)cc * EDIM + rr] = f2bf(v);
    else {
      const int row = ((cc >> 4) << 5) + (cc & 15) + (type << 4);  // gate/up interleave
      dst[(size_t)row * DIM + rr] = f2bf(v);
    }
  }
}

// ---- single-block prefix scan -> one compacted expert-sorted rowlist --------
__global__ void scan_k(const int* __restrict__ choice, int* __restrict__ counts,
                       int* __restrict__ rowlist) {
  const int t = threadIdx.x;            // 1024 threads, one block
  const int base = t * 8;
  int c[8]; int ones = 0;
  #pragma unroll
  for (int j = 0; j < 8; ++j) { c[j] = choice[base + j]; ones += c[j]; }
  const int lane = t & 63, wid = t >> 6;
  int v = ones;
  #pragma unroll
  for (int off = 1; off < 64; off <<= 1) {
    int o = __shfl_up(v, off);
    if (lane >= off) v += o;
  }
  __shared__ int wsum[16];
  if (lane == 63) wsum[wid] = v;
  __syncthreads();
  int pre = 0, tot = 0;
  #pragma unroll
  for (int w = 0; w < 16; ++w) {
    int s = wsum[w];
    if (w < wid) pre += s;
    tot += s;
  }
  const int excl = pre + v - ones;      // ones strictly before token `base`
  const int cnt0 = NTOK - tot;
  int p0 = base - excl;                 // zeros position
  int p1 = cnt0 + excl;                 // ones position (after expert-0 segment)
  #pragma unroll
  for (int j = 0; j < 8; ++j) {
    if (c[j]) rowlist[p1++] = base + j;
    else rowlist[p0++] = base + j;
  }
  if (t == 0) { counts[0] = cnt0; counts[1] = tot; }
}

// ---- unified m97-style 128x128 MFMA GEMM, 256 thr, 32KB LDS, 4 blocks/CU ----
// MODE 0: up shared  (A=xb linear,   B=Sgu,    write h[row]        silu*u)
// MODE 1: up routed  (A=xb gathered, B=Wgu_e,  write h[compacted]  silu*u)
// MODE 2: down shared(A=h linear,    B=Sdt,    out[row] = )
// MODE 3: down routed(A=h compacted, B=Wdt_e,  out[rl[row]] += scatter)
template<int KDIM, int MODE>
__global__ __launch_bounds__(256, 4)
void gemm2_k(const unsigned short* __restrict__ A, const unsigned short* __restrict__ B0,
             const int* __restrict__ counts, const int* __restrict__ rl,
             unsigned short* __restrict__ h, float* __restrict__ out) {
  constexpr int NT = KDIM / 64;
  constexpr int ROWB = KDIM * 2;

  int e = 0, mstart = 0, cntE = NTOK, r0;
  if (MODE == 1 || MODE == 3) {
    e = blockIdx.x >> 6;
    const int mt = blockIdx.x & 63;
    const int c0 = counts[0];
    cntE = e ? (NTOK - c0) : c0;
    mstart = e ? c0 : 0;
    r0 = mt * 128;
    if (r0 >= cntE) return;
  } else {
    r0 = blockIdx.x * 128;
  }
  const int n0 = blockIdx.y * 128;
  const unsigned short* B = B0;
  if (MODE == 1) B += (size_t)e * 4194304u;
  if (MODE == 3) B += (size_t)e * 2097152u;

  __shared__ __align__(16) unsigned char lA[16384];
  __shared__ __align__(16) unsigned char lB[16384];

  const int t = threadIdx.x;
  const int lane = t & 63;
  const int wm = t >> 7, wn = (t >> 6) & 1;
  const int l15 = lane & 15, l4 = lane >> 4;

  size_t aoff[4]; uint32_t boff[4]; int dsto[4];
  #pragma unroll
  for (int i = 0; i < 4; ++i) {
    const int flat = i * 4096 + t * 16;
    const int row = flat >> 7;
    const int kb = (flat & 127) ^ ((row & 7) << 4);
    int ar;
    if (MODE == 1) {
      int idx = r0 + row; if (idx >= cntE) idx = cntE - 1;
      ar = rl[mstart + idx];
    } else if (MODE == 3) {
      int idx = r0 + row; if (idx >= cntE) idx = cntE - 1;
      ar = mstart + idx;
    } else {
      ar = r0 + row;
    }
    aoff[i] = (size_t)ar * ROWB + kb;
    boff[i] = (uint32_t)(n0 + row) * ROWB + kb;
    dsto[i] = flat;
  }

  f32x4 acc[4][4];
  #pragma unroll
  for (int i = 0; i < 4; ++i)
    #pragma unroll
    for (int j = 0; j < 4; ++j) acc[i][j] = f32x4{0.f, 0.f, 0.f, 0.f};

  const char* Ab = (const char*)A;
  const char* Bb = (const char*)B;

  for (int kt = 0; kt < NT; ++kt) {
    __syncthreads();
    const size_t ko = (size_t)kt * 128;
    #pragma unroll
    for (int i = 0; i < 4; ++i) {
      gload16(Ab + aoff[i] + ko, lA + dsto[i]);
      gload16(Bb + boff[i] + ko, lB + dsto[i]);
    }
    __syncthreads();
    #pragma unroll
    for (int ks = 0; ks < 2; ++ks) {
      bf16x8 af[4], bf[4];
      const int kb = ks * 64 + (l4 << 4);
      #pragma unroll
      for (int mi = 0; mi < 4; ++mi) {
        const int row = wm * 64 + mi * 16 + l15;
        af[mi] = *(const bf16x8*)(lA + row * 128 + (kb ^ ((row & 7) << 4)));
      }
      #pragma unroll
      for (int ni = 0; ni < 4; ++ni) {
        const int col = wn * 64 + ni * 16 + l15;
        bf[ni] = *(const bf16x8*)(lB + col * 128 + (kb ^ ((col & 7) << 4)));
      }
      #pragma unroll
      for (int mi = 0; mi < 4; ++mi)
        #pragma unroll
        for (int ni = 0; ni < 4; ++ni)
          acc[mi][ni] = __builtin_amdgcn_mfma_f32_16x16x32_bf16(af[mi], bf[ni], acc[mi][ni], 0, 0, 0);
    }
  }

  // epilogue
  #pragma unroll
  for (int mi = 0; mi < 4; ++mi) {
    #pragma unroll
    for (int r = 0; r < 4; ++r) {
      const int rit = wm * 64 + mi * 16 + l4 * 4 + r;
      if (MODE == 0 || MODE == 1) {
        const int pos = r0 + rit;
        if (MODE == 1 && pos >= cntE) continue;
        unsigned short* hr = h + (size_t)(mstart + pos) * EDIM;
        const int f0 = (n0 >> 1) + wn * 32;
        #pragma unroll
        for (int j = 0; j < 2; ++j) {
          const float g = acc[mi][2 * j][r], u = acc[mi][2 * j + 1][r];
          hr[f0 + j * 16 + l15] = f2bf(g / (1.f + __expf(-g)) * u);
        }
      } else if (MODE == 2) {
        float* orow = out + (size_t)(r0 + rit) * DIM;
        #pragma unroll
        for (int n = 0; n < 4; ++n)
          orow[n0 + wn * 64 + n * 16 + l15] = acc[mi][n][r];
      } else {
        const int pos = r0 + rit;
        if (pos >= cntE) continue;
        const int tok = rl[mstart + pos];
        float* orow = out + (size_t)tok * DIM;
        #pragma unroll
        for (int n = 0; n < 4; ++n)
          orow[n0 + wn * 64 + n * 16 + l15] += acc[mi][n][r];
      }
    }
  }
}

extern "C" void kernel_launch(void* const* d_in, const int* in_sizes, int n_in,
                              void* d_out, int out_size, void* d_ws, size_t ws_size,
                              hipStream_t stream) {
  const float* x  = (const float*)d_in[0];
  const float* Wr = (const float*)d_in[1];
  const float* rb = (const float*)d_in[2];
  const float* Wg = (const float*)d_in[3];
  const float* Wu = (const float*)d_in[4];
  const float* Wd = (const float*)d_in[5];
  const float* Sg = (const float*)d_in[6];
  const float* Su = (const float*)d_in[7];
  const float* Sd = (const float*)d_in[8];
  float* out = (float*)d_out;

  char* ws = (char*)d_ws;
  int* counts  = (int*)ws;                                 // 256 B
  int* choice  = (int*)(ws + 256);                         // 32 KiB
  int* rowlist = (int*)(ws + 256 + 32768);                 // 32 KiB (8192 compacted)
  unsigned short* xb = (unsigned short*)(ws + 256 + 65536);
  unsigned short* wt = xb + (size_t)NTOK * DIM;            // 18M elems of weights
  unsigned short* h  = wt + 18874368;                      // [8192][2048] bf16 (reused)

  const unsigned short* Sgu  = wt;             // [4096][1024] gate/up interleaved
  const unsigned short* Wgu0 = wt + 4194304;   // 2 x [4096][1024]
  const unsigned short* Sdt  = wt + 12582912;  // [1024][2048]
  const unsigned short* Wdt0 = wt + 14680064;  // 2 x [1024][2048]

  pre_k<<<1024 + 9 * 2048, 256, 0, stream>>>(x, Wr, rb, Sg, Su, Sd, Wg, Wu, Wd,
                                             xb, choice, wt);
  scan_k<<<1, 1024, 0, stream>>>(choice, counts, rowlist);

  // shared expert: up -> h (all tokens), down -> out (=)
  gemm2_k<DIM, 0><<<dim3(64, 32), 256, 0, stream>>>(xb, Sgu, counts, rowlist, h, nullptr);
  gemm2_k<EDIM, 2><<<dim3(64, 8), 256, 0, stream>>>(h, Sdt, counts, rowlist, nullptr, out);
  // routed experts: up (gather) -> h compacted, down -> out (scatter +=)
  gemm2_k<DIM, 1><<<dim3(128, 32), 256, 0, stream>>>(xb, Wgu0, counts, rowlist, h, nullptr);
  gemm2_k<EDIM, 3><<<dim3(128, 8), 256, 0, stream>>>(h, Wdt0, counts, rowlist, nullptr, out);
}